// Round 4
// baseline (1107.369 us; speedup 1.0000x reference)
//
#include <hip/hip_runtime.h>
#include <hip/hip_bf16.h>

#define DI __device__ __forceinline__

DI float fmulr(float a, float b){ return __fmul_rn(a,b); }
DI float faddr(float a, float b){ return __fadd_rn(a,b); }
DI float fsubr(float a, float b){ return __fsub_rn(a,b); }
DI float dist2e(float x,float y,float z,float cx,float cy,float cz){
  float dx=fsubr(x,cx), dy=fsubr(y,cy), dz=fsubr(z,cz);
  return faddr(faddr(fmulr(dx,dx),fmulr(dy,dy)),fmulr(dz,dz));
}
DI unsigned short f2bf(float f){ __hip_bfloat16 h=__float2bfloat16(f); return *reinterpret_cast<unsigned short*>(&h); }

// ---------------- FPS: 8 blocks (one per batch), 256 threads, 16 pts/lane ----------------
// No global memory ops inside the iteration loop (a global store before
// __syncthreads forces a vmcnt(0) drain on the critical path every iteration).
// Thread tid records centroid indices for iterations t = tid (mod 256) in
// registers; coordinates are written once at the end from the LDS copy.
__global__ __launch_bounds__(256) void fps_kernel(const float* __restrict__ xyz, float* __restrict__ out0){
  __shared__ float sp[12288];
  __shared__ unsigned long long slots[2][4];
  int b=blockIdx.x, tid=threadIdx.x;
  const float* xb = xyz + (size_t)b*4096*3;
  const float4* src=(const float4*)xb; float4* dst=(float4*)sp;
  #pragma unroll
  for(int i=0;i<12;i++) dst[i*256+tid]=src[i*256+tid];
  __syncthreads();
  float px[16],py[16],pz[16],dist[16];
  int p0 = tid*16;
  #pragma unroll
  for(int j=0;j<16;j++){ px[j]=sp[3*(p0+j)]; py[j]=sp[3*(p0+j)+1]; pz[j]=sp[3*(p0+j)+2]; dist[j]=1e10f; }
  int cur=0;
  float cx=sp[0], cy=sp[1], cz=sp[2];
  int w=tid>>6, lane=tid&63;
  int c0s=0,c1s=0,c2s=0,c3s=0;
  float* ob = out0 + (size_t)b*1024*3;
  #pragma unroll 1
  for(int t=0;t<1024;t++){
    // record the centroid used this iteration (pre-update cur)
    bool mine = ((t&255)==tid);
    int hi = t>>8;
    c0s = (mine && hi==0) ? cur : c0s;
    c1s = (mine && hi==1) ? cur : c1s;
    c2s = (mine && hi==2) ? cur : c2s;
    c3s = (mine && hi==3) ? cur : c3s;
    float nd[16];
    #pragma unroll
    for(int j=0;j<16;j++){
      float d=dist2e(px[j],py[j],pz[j],cx,cy,cz);
      float m=fminf(dist[j],d); dist[j]=m; nd[j]=m;
    }
    // tree max (short dependent chain), then first-occurrence index via mask
    float a0=fmaxf(nd[0],nd[1]), a1=fmaxf(nd[2],nd[3]), a2=fmaxf(nd[4],nd[5]), a3=fmaxf(nd[6],nd[7]);
    float a4=fmaxf(nd[8],nd[9]), a5=fmaxf(nd[10],nd[11]), a6=fmaxf(nd[12],nd[13]), a7=fmaxf(nd[14],nd[15]);
    float b0=fmaxf(a0,a1), b1=fmaxf(a2,a3), b2=fmaxf(a4,a5), b3=fmaxf(a6,a7);
    float bv=fmaxf(fmaxf(b0,b1),fmaxf(b2,b3));
    unsigned msk=0u;
    #pragma unroll
    for(int j=0;j<16;j++) msk |= (nd[j]==bv) ? (1u<<j) : 0u;
    int bj=__ffs(msk)-1;
    int bi=p0+bj;
    // value-only wave butterfly
    float wv = bv;
    #pragma unroll
    for(int m=32;m>=1;m>>=1) wv = fmaxf(wv, __shfl_xor(wv,m));
    unsigned long long mask = __ballot(bv==wv);
    int L = (int)(__ffsll((unsigned long long)mask)-1);
    int wbi = __shfl(bi, L);
    if(lane==0) slots[t&1][w] = ((unsigned long long)__float_as_uint(wv)<<32)
                              | (unsigned long long)(0xFFFFFFFFu-(unsigned)wbi);
    __syncthreads();
    unsigned long long k = slots[t&1][0];
    #pragma unroll
    for(int j=1;j<4;j++){ unsigned long long ok=slots[t&1][j]; if(ok>k) k=ok; }
    cur = (int)(0xFFFFFFFFu - (unsigned)(k & 0xFFFFFFFFull));
    cx=sp[3*cur]; cy=sp[3*cur+1]; cz=sp[3*cur+2];
  }
  // write the 4 centers this thread recorded
  { int t0=tid;     ob[t0*3]=sp[3*c0s]; ob[t0*3+1]=sp[3*c0s+1]; ob[t0*3+2]=sp[3*c0s+2]; }
  { int t1=tid+256; ob[t1*3]=sp[3*c1s]; ob[t1*3+1]=sp[3*c1s+1]; ob[t1*3+2]=sp[3*c1s+2]; }
  { int t2=tid+512; ob[t2*3]=sp[3*c2s]; ob[t2*3+1]=sp[3*c2s+1]; ob[t2*3+2]=sp[3*c2s+2]; }
  { int t3=tid+768; ob[t3*3]=sp[3*c3s]; ob[t3*3+1]=sp[3*c3s+1]; ob[t3*3+2]=sp[3*c3s+2]; }
}

// ---------------- ball query: 4 waves/block share one batch staged in LDS ----------------
__global__ __launch_bounds__(256) void ballq_kernel(const float* __restrict__ xyz, const float* __restrict__ out0,
        int* __restrict__ idxw, float* __restrict__ out2){
  __shared__ float sp[12288];
  int tid=threadIdx.x;
  int g = blockIdx.x*4 + (tid>>6);
  int lane = tid&63;
  int b = blockIdx.x>>8;
  const float* xb = xyz + (size_t)b*4096*3;
  const float4* src=(const float4*)xb; float4* dst=(float4*)sp;
  #pragma unroll
  for(int i=0;i<12;i++) dst[i*256+tid]=src[i*256+tid];
  __syncthreads();
  float cx=out0[(size_t)g*3], cy=out0[(size_t)g*3+1], cz=out0[(size_t)g*3+2];
  const float R2 = (float)(0.2*0.2);
  int cnt=0, firstp=0; bool haveFirst=false;
  for(int c=0;c<64;c++){
    int p=c*64+lane;
    float x=sp[3*p], y=sp[3*p+1], z=sp[3*p+2];
    float d2=dist2e(x,y,z,cx,cy,cz);
    bool inb = d2 < R2;
    unsigned long long mask=__ballot(inb);
    if(!haveFirst && mask){ firstp = c*64 + (__ffsll((unsigned long long)mask)-1); haveFirst=true; }
    int pos = cnt + (int)__popcll(mask & ((1ull<<lane)-1ull));
    if(inb && pos<32){ idxw[(size_t)g*32+pos]=p; out2[(size_t)g*32+pos]=(float)p; }
    cnt += (int)__popcll(mask);
    if(cnt>=32) break;
  }
  if(cnt<32){
    for(int j=cnt+lane; j<32; j+=64){ idxw[(size_t)g*32+j]=firstp; out2[(size_t)g*32+j]=(float)firstp; }
  }
}

// ---------------- M = Wq * Wk^T  (3x128) ----------------
__global__ void m_kernel(const float* __restrict__ Wq, const float* __restrict__ Wk, float* __restrict__ M){
  int c = threadIdx.x; // 128
  float m0=0.f,m1=0.f,m2=0.f;
  for(int d=0; d<128; d++){
    float wk = Wk[c*128+d];
    m0 += Wq[d]*wk; m1 += Wq[128+d]*wk; m2 += Wq[256+d]*wk;
  }
  M[c]=m0; M[128+c]=m1; M[256+c]=m2;
}

// ---------------- layer0: gather + (67->64) matmul + bias + partial stats ----------------
__global__ __launch_bounds__(256) void l0_kernel(const float* __restrict__ xyz, const float* __restrict__ pts,
    const float* __restrict__ out0, const int* __restrict__ idxw,
    const float* __restrict__ W0, const float* __restrict__ b0,
    __hip_bfloat16* __restrict__ y0, float* __restrict__ P){
  __shared__ float xl[64*69];
  int tid=threadIdx.x; int base=blockIdx.x*64;
  int w=tid>>6, lane=tid&63;
  for(int i=0;i<16;i++){
    int r=w*16+i; int R=base+r;
    int g=R>>5; int b=g>>10; int p=idxw[R];
    const float* prow = pts + ((size_t)b*4096 + (size_t)p)*64;
    xl[r*69+3+lane] = prow[lane];
    if(lane<3){
      xl[r*69+lane] = fsubr(xyz[((size_t)b*4096+(size_t)p)*3+lane], out0[(size_t)g*3+lane]);
    }
  }
  __syncthreads();
  int r=tid&63;
  int cgu=__builtin_amdgcn_readfirstlane(tid>>6);
  float acc[16];
  #pragma unroll
  for(int j=0;j<16;j++) acc[j]=b0[cgu*16+j];
  for(int c=0;c<67;c++){
    float xv=xl[r*69+c];
    #pragma unroll
    for(int j=0;j<16;j++) acc[j] += xv*W0[c*64+cgu*16+j];
  }
  size_t R=(size_t)base+r;
  unsigned short tb[16];
  #pragma unroll
  for(int j=0;j<16;j++) tb[j]=f2bf(acc[j]);
  uint4* ov=(uint4*)(y0 + R*64 + cgu*16);
  ov[0]=make_uint4(tb[0]|(tb[1]<<16), tb[2]|(tb[3]<<16), tb[4]|(tb[5]<<16), tb[6]|(tb[7]<<16));
  ov[1]=make_uint4(tb[8]|(tb[9]<<16), tb[10]|(tb[11]<<16), tb[12]|(tb[13]<<16), tb[14]|(tb[15]<<16));
  #pragma unroll
  for(int j=0;j<16;j++){
    float s=acc[j], q=acc[j]*acc[j];
    #pragma unroll
    for(int m=32;m>=1;m>>=1){ s+=__shfl_xor(s,m); q+=__shfl_xor(q,m); }
    if(r==0){ P[(size_t)(cgu*16+j)*4096 + blockIdx.x]=s; P[(size_t)(128+cgu*16+j)*4096 + blockIdx.x]=q; }
  }
}

// ---------------- mid layers: bn(prev)+relu on load, matmul, bias, partial stats ----------------
template<int CIN,int COUT>
__global__ __launch_bounds__(256) void lmid_kernel(const __hip_bfloat16* __restrict__ xin,
    const float* __restrict__ ssIn, const float* __restrict__ W, const float* __restrict__ bias,
    __hip_bfloat16* __restrict__ yout, float* __restrict__ P){
  constexpr int STR=CIN+1;
  constexpr int PER=COUT/4;
  __shared__ float xl[64*STR];
  int tid=threadIdx.x; size_t base=(size_t)blockIdx.x*64;
  constexpr int CHUNKS = 64*CIN/8;
  #pragma unroll
  for(int i=0;i<CHUNKS/256;i++){
    int e=i*256+tid;
    int r=e/(CIN/8), c0=(e%(CIN/8))*8;
    uint4 raw = *reinterpret_cast<const uint4*>(xin + (base+(size_t)r)*CIN + c0);
    unsigned u[4]={raw.x,raw.y,raw.z,raw.w};
    #pragma unroll
    for(int k=0;k<4;k++){
      int c=c0+2*k;
      float lo=__uint_as_float(u[k]<<16);
      float hi=__uint_as_float(u[k]&0xFFFF0000u);
      float a=lo*ssIn[c]+ssIn[128+c];
      float bq=hi*ssIn[c+1]+ssIn[128+c+1];
      xl[r*STR+c]  = a>0.f?a:0.f;
      xl[r*STR+c+1]= bq>0.f?bq:0.f;
    }
  }
  __syncthreads();
  int r=tid&63;
  int cgu=__builtin_amdgcn_readfirstlane(tid>>6);
  float acc[PER];
  #pragma unroll
  for(int j=0;j<PER;j++) acc[j]=bias[cgu*PER+j];
  for(int c=0;c<CIN;c++){
    float xv=xl[r*STR+c];
    #pragma unroll
    for(int j=0;j<PER;j++) acc[j] += xv*W[c*COUT+cgu*PER+j];
  }
  size_t R=base+r;
  unsigned short tb[PER];
  #pragma unroll
  for(int j=0;j<PER;j++) tb[j]=f2bf(acc[j]);
  uint4* ov=(uint4*)(yout + R*COUT + cgu*PER);
  #pragma unroll
  for(int v=0;v<PER/8;v++)
    ov[v]=make_uint4(tb[v*8]|(tb[v*8+1]<<16), tb[v*8+2]|(tb[v*8+3]<<16), tb[v*8+4]|(tb[v*8+5]<<16), tb[v*8+6]|(tb[v*8+7]<<16));
  #pragma unroll
  for(int j=0;j<PER;j++){
    float s=acc[j],q=acc[j]*acc[j];
    #pragma unroll
    for(int m=32;m>=1;m>>=1){s+=__shfl_xor(s,m);q+=__shfl_xor(q,m);}
    if(r==0){ P[(size_t)(cgu*PER+j)*4096 + blockIdx.x]=s; P[(size_t)(128+cgu*PER+j)*4096 + blockIdx.x]=q; }
  }
}

// ---------------- finalize stats: scale/shift per channel ----------------
__global__ void fin_kernel(const float* __restrict__ P, const float* __restrict__ gg, const float* __restrict__ be,
                           float* __restrict__ ss){
  int ch=blockIdx.x; int lane=threadIdx.x;
  float s=0.f,q=0.f;
  for(int blk=lane; blk<4096; blk+=64){ s+=P[(size_t)ch*4096+blk]; q+=P[(size_t)(128+ch)*4096+blk]; }
  #pragma unroll
  for(int m=32;m>=1;m>>=1){ s+=__shfl_xor(s,m); q+=__shfl_xor(q,m); }
  if(lane==0){
    const float invNT = 1.0f/262144.0f;
    float mean=s*invNT; float var=q*invNT - mean*mean;
    float scale=gg[ch]/sqrtf(var+1e-3f);
    ss[ch]=scale; ss[128+ch]=be[ch]-mean*scale;
  }
}

// ---------------- per-group: bn2+relu, u=center@M, scores, softmax, hbar ----------------
__global__ __launch_bounds__(256) void sh_kernel(const __hip_bfloat16* __restrict__ y2,
    const float* __restrict__ ss2, const float* __restrict__ M, const float* __restrict__ out0,
    float* __restrict__ hbar){
  __shared__ float h[2][32*130];
  __shared__ float uLds[2][128];
  __shared__ float sLds[2][32];
  int tid=threadIdx.x; int grp=tid>>7, t=tid&127;
  size_t g=(size_t)blockIdx.x*2+grp;
  #pragma unroll
  for(int i=0;i<4;i++){
    int e=i*128+t;
    int row=e>>4, c0=(e&15)*8;
    uint4 raw=*reinterpret_cast<const uint4*>(y2+(g*32+(size_t)row)*128+c0);
    unsigned u[4]={raw.x,raw.y,raw.z,raw.w};
    #pragma unroll
    for(int k=0;k<4;k++){
      int c=c0+2*k;
      float lo=__uint_as_float(u[k]<<16), hi=__uint_as_float(u[k]&0xFFFF0000u);
      float a=lo*ss2[c]+ss2[128+c]; float bq=hi*ss2[c+1]+ss2[128+c+1];
      h[grp][row*130+c]  = a>0.f?a:0.f;
      h[grp][row*130+c+1]= bq>0.f?bq:0.f;
    }
  }
  float cx=out0[g*3], cy=out0[g*3+1], cz=out0[g*3+2];
  uLds[grp][t]=cx*M[t]+cy*M[128+t]+cz*M[256+t];
  __syncthreads();
  if(t<32){
    float sc=0.f;
    for(int c=0;c<128;c++) sc+=h[grp][t*130+c]*uLds[grp][c];
    sc*=0.08838834764831845f; // 1/sqrt(128)
    float mx=sc;
    #pragma unroll
    for(int m=16;m>=1;m>>=1) mx=fmaxf(mx,__shfl_xor(mx,m));
    float p=expf(sc-mx);
    float sum=p;
    #pragma unroll
    for(int m=16;m>=1;m>>=1) sum+=__shfl_xor(sum,m);
    sLds[grp][t]=p/sum;
  }
  __syncthreads();
  float hb=0.f;
  for(int k=0;k<32;k++) hb+=sLds[grp][k]*h[grp][k*130+t];
  hbar[g*128+t]=hb;
}

// ---------------- pooled = hbar @ Wv ----------------
__global__ __launch_bounds__(256) void pool_kernel(const float* __restrict__ hbar, const float* __restrict__ Wv,
    float* __restrict__ out1){
  __shared__ float xl[32*129];
  int tid=threadIdx.x; size_t g0=(size_t)blockIdx.x*32;
  for(int e=tid;e<32*128;e+=256){ int r=e>>7,ch=e&127; xl[r*129+ch]=hbar[(g0+(size_t)r)*128+ch]; }
  __syncthreads();
  int r=tid&31;
  int cgu=__builtin_amdgcn_readfirstlane(tid>>5);
  float acc[16];
  #pragma unroll
  for(int j=0;j<16;j++) acc[j]=0.f;
  for(int c=0;c<128;c++){
    float xv=xl[r*129+c];
    #pragma unroll
    for(int j=0;j<16;j++) acc[j]+=xv*Wv[c*128+cgu*16+j];
  }
  #pragma unroll
  for(int j=0;j<16;j++) out1[(g0+(size_t)r)*128+cgu*16+j]=acc[j];
}

extern "C" void kernel_launch(void* const* d_in, const int* in_sizes, int n_in,
                              void* d_out, int out_size, void* d_ws, size_t ws_size,
                              hipStream_t stream){
  (void)in_sizes; (void)n_in; (void)out_size; (void)ws_size;
  const float* xyz=(const float*)d_in[0];
  const float* pts=(const float*)d_in[1];
  const float* W0=(const float*)d_in[2];  const float* b0=(const float*)d_in[3];
  const float* g0=(const float*)d_in[4];  const float* be0=(const float*)d_in[5];
  const float* W1=(const float*)d_in[6];  const float* b1=(const float*)d_in[7];
  const float* g1=(const float*)d_in[8];  const float* be1=(const float*)d_in[9];
  const float* W2=(const float*)d_in[10]; const float* b2=(const float*)d_in[11];
  const float* g2=(const float*)d_in[12]; const float* be2=(const float*)d_in[13];
  const float* Wq=(const float*)d_in[14]; const float* Wk=(const float*)d_in[15];
  const float* Wv=(const float*)d_in[16];
  float* out0=(float*)d_out;
  float* out1=out0 + (size_t)8*1024*3;
  float* out2=out1 + (size_t)8192*128;

  char* ws=(char*)d_ws; size_t off=0;
  int* idxw=(int*)(ws+off);                    off += (size_t)8192*32*4;
  __hip_bfloat16* fa=(__hip_bfloat16*)(ws+off); off += (size_t)262144*64*2;
  __hip_bfloat16* fb=(__hip_bfloat16*)(ws+off); off += (size_t)262144*64*2;
  __hip_bfloat16* fc=(__hip_bfloat16*)(ws+off); off += (size_t)262144*128*2;
  float* P =(float*)(ws+off);                  off += (size_t)256*4096*4;
  float* ss0=(float*)(ws+off);                 off += 256*4;
  float* ss1=(float*)(ws+off);                 off += 256*4;
  float* ss2=(float*)(ws+off);                 off += 256*4;
  float* M =(float*)(ws+off);                  off += 3*128*4 + 128;
  float* hb=(float*)(ws+off);                  off += (size_t)8192*128*4;

  hipLaunchKernelGGL(fps_kernel,   dim3(8),    dim3(256),  0, stream, xyz, out0);
  hipLaunchKernelGGL(ballq_kernel, dim3(2048), dim3(256),  0, stream, xyz, out0, idxw, out2);
  hipLaunchKernelGGL(m_kernel,     dim3(1),    dim3(128),  0, stream, Wq, Wk, M);
  hipLaunchKernelGGL(l0_kernel,    dim3(4096), dim3(256),  0, stream, xyz, pts, out0, idxw, W0, b0, fa, P);
  hipLaunchKernelGGL(fin_kernel,   dim3(64),   dim3(64),   0, stream, P, g0, be0, ss0);
  hipLaunchKernelGGL((lmid_kernel<64,64>),  dim3(4096), dim3(256), 0, stream, fa, ss0, W1, b1, fb, P);
  hipLaunchKernelGGL(fin_kernel,   dim3(64),   dim3(64),   0, stream, P, g1, be1, ss1);
  hipLaunchKernelGGL((lmid_kernel<64,128>), dim3(4096), dim3(256), 0, stream, fb, ss1, W2, b2, fc, P);
  hipLaunchKernelGGL(fin_kernel,   dim3(128),  dim3(64),   0, stream, P, g2, be2, ss2);
  hipLaunchKernelGGL(sh_kernel,    dim3(4096), dim3(256),  0, stream, fc, ss2, M, out0, hb);
  hipLaunchKernelGGL(pool_kernel,  dim3(256),  dim3(256),  0, stream, hb, Wv, out1);
}

// Round 5
// 970.681 us; speedup vs baseline: 1.1408x; 1.1408x over previous
//
#include <hip/hip_runtime.h>
#include <hip/hip_bf16.h>

#define DI __device__ __forceinline__

DI float fmulr(float a, float b){ return __fmul_rn(a,b); }
DI float faddr(float a, float b){ return __fadd_rn(a,b); }
DI float fsubr(float a, float b){ return __fsub_rn(a,b); }
DI float dist2e(float x,float y,float z,float cx,float cy,float cz){
  float dx=fsubr(x,cx), dy=fsubr(y,cy), dz=fsubr(z,cz);
  return faddr(faddr(fmulr(dx,dx),fmulr(dy,dy)),fmulr(dz,dz));
}
DI unsigned short f2bf(float f){ __hip_bfloat16 h=__float2bfloat16(f); return *reinterpret_cast<unsigned short*>(&h); }

// DPP-based wave64 max: row_shr 1/2/4/8 then row_bcast:15, row_bcast:31 -> lane63 holds max.
template<int C> DI float dmax_step(float x){
  int y=__builtin_amdgcn_update_dpp(0, __float_as_int(x), C, 0xF, 0xF, true);
  return fmaxf(x, __int_as_float(y));
}

// ---------------- FPS: 8 blocks (one per batch), 256 threads, 16 pts/lane ----------------
// Points live in sp4[4096] (float4-padded, 64KB LDS) so the centroid fetch is one
// ds_read_b128. Cross-wave argmax slots are stored in the unused .w components of
// points 0..15 (keeps LDS at the 64KB static cap). Wave reduction is value-only DPP
// max + ballot/ffs/readlane for the first-occurrence index (bit-exact tie semantics:
// ownership is consecutive, lowest lane == lowest index).
__global__ __launch_bounds__(256) void fps_kernel(const float* __restrict__ xyz, float* __restrict__ out0){
  __shared__ float4 sp4[4096];
  float* spf=(float*)sp4;
  int* spi=(int*)sp4;
  int b=blockIdx.x, tid=threadIdx.x;
  const float* xb = xyz + (size_t)b*4096*3;
  for(int e=tid;e<12288;e+=256){
    int p=e/3, c=e-3*p;
    spf[4*p+c]=xb[e];
  }
  __syncthreads();
  float px[16],py[16],pz[16],dist[16];
  int p0 = tid*16;
  #pragma unroll
  for(int j=0;j<16;j++){ float4 r=sp4[p0+j]; px[j]=r.x; py[j]=r.y; pz[j]=r.z; dist[j]=1e10f; }
  int cur=0;
  float4 cc0=sp4[0];
  float cx=cc0.x, cy=cc0.y, cz=cc0.z;
  int w=tid>>6, lane=tid&63;
  int c0s=0,c1s=0,c2s=0,c3s=0;
  float* ob = out0 + (size_t)b*1024*3;
  #pragma unroll 1
  for(int t=0;t<1024;t++){
    bool mine = ((t&255)==tid);
    int hi = t>>8;
    c0s = (mine && hi==0) ? cur : c0s;
    c1s = (mine && hi==1) ? cur : c1s;
    c2s = (mine && hi==2) ? cur : c2s;
    c3s = (mine && hi==3) ? cur : c3s;
    float nd[16];
    #pragma unroll
    for(int j=0;j<16;j++){
      float d=dist2e(px[j],py[j],pz[j],cx,cy,cz);
      float m=fminf(dist[j],d); dist[j]=m; nd[j]=m;
    }
    float a0=fmaxf(nd[0],nd[1]), a1=fmaxf(nd[2],nd[3]), a2=fmaxf(nd[4],nd[5]), a3=fmaxf(nd[6],nd[7]);
    float a4=fmaxf(nd[8],nd[9]), a5=fmaxf(nd[10],nd[11]), a6=fmaxf(nd[12],nd[13]), a7=fmaxf(nd[14],nd[15]);
    float b0=fmaxf(a0,a1), b1=fmaxf(a2,a3), b2=fmaxf(a4,a5), b3=fmaxf(a6,a7);
    float bv=fmaxf(fmaxf(b0,b1),fmaxf(b2,b3));
    unsigned msk=0u;
    #pragma unroll
    for(int j=0;j<16;j++) msk |= (nd[j]==bv) ? (1u<<j) : 0u;
    int bj=__ffs(msk)-1;
    int bi=p0+bj;
    // DPP value-only wave max
    float x=bv;
    x=dmax_step<0x111>(x); x=dmax_step<0x112>(x); x=dmax_step<0x114>(x); x=dmax_step<0x118>(x);
    x=dmax_step<0x142>(x); x=dmax_step<0x143>(x);
    float wv=__int_as_float(__builtin_amdgcn_readlane(__float_as_int(x),63));
    unsigned long long em=__ballot(bv==wv);
    int L=(int)(__ffsll(em)-1);
    int wbi=__builtin_amdgcn_readlane(bi,L);
    int par=t&1;
    if(lane==0){
      spf[4*(par*8+w)+3]=wv;            // value slot (w-component of point par*8+w)
      spi[4*(par*8+4+w)+3]=wbi;         // index slot (w-component of point par*8+4+w)
    }
    __syncthreads();
    float w0=spf[4*(par*8+0)+3], w1=spf[4*(par*8+1)+3], w2=spf[4*(par*8+2)+3], w3=spf[4*(par*8+3)+3];
    int   i0=spi[4*(par*8+4)+3], i1=spi[4*(par*8+5)+3], i2=spi[4*(par*8+6)+3], i3=spi[4*(par*8+7)+3];
    float mv=fmaxf(fmaxf(w0,w1),fmaxf(w2,w3));
    int u0=(w0==mv)?i0:0x7fffffff, u1=(w1==mv)?i1:0x7fffffff;
    int u2=(w2==mv)?i2:0x7fffffff, u3=(w3==mv)?i3:0x7fffffff;
    cur=min(min(u0,u1),min(u2,u3));
    float4 cc=sp4[cur]; cx=cc.x; cy=cc.y; cz=cc.z;
  }
  { int t0=tid;     float4 c=sp4[c0s]; ob[t0*3]=c.x; ob[t0*3+1]=c.y; ob[t0*3+2]=c.z; }
  { int t1=tid+256; float4 c=sp4[c1s]; ob[t1*3]=c.x; ob[t1*3+1]=c.y; ob[t1*3+2]=c.z; }
  { int t2=tid+512; float4 c=sp4[c2s]; ob[t2*3]=c.x; ob[t2*3+1]=c.y; ob[t2*3+2]=c.z; }
  { int t3=tid+768; float4 c=sp4[c3s]; ob[t3*3]=c.x; ob[t3*3+1]=c.y; ob[t3*3+2]=c.z; }
}

// ---------------- ball query: 4 waves/block share one batch staged in LDS ----------------
__global__ __launch_bounds__(256) void ballq_kernel(const float* __restrict__ xyz, const float* __restrict__ out0,
        int* __restrict__ idxw, float* __restrict__ out2){
  __shared__ float sp[12288];
  int tid=threadIdx.x;
  int g = blockIdx.x*4 + (tid>>6);
  int lane = tid&63;
  int b = blockIdx.x>>8;
  const float* xb = xyz + (size_t)b*4096*3;
  const float4* src=(const float4*)xb; float4* dst=(float4*)sp;
  #pragma unroll
  for(int i=0;i<12;i++) dst[i*256+tid]=src[i*256+tid];
  __syncthreads();
  float cx=out0[(size_t)g*3], cy=out0[(size_t)g*3+1], cz=out0[(size_t)g*3+2];
  const float R2 = (float)(0.2*0.2);
  int cnt=0, firstp=0; bool haveFirst=false;
  for(int c=0;c<64;c++){
    int p=c*64+lane;
    float x=sp[3*p], y=sp[3*p+1], z=sp[3*p+2];
    float d2=dist2e(x,y,z,cx,cy,cz);
    bool inb = d2 < R2;
    unsigned long long mask=__ballot(inb);
    if(!haveFirst && mask){ firstp = c*64 + (__ffsll((unsigned long long)mask)-1); haveFirst=true; }
    int pos = cnt + (int)__popcll(mask & ((1ull<<lane)-1ull));
    if(inb && pos<32){ idxw[(size_t)g*32+pos]=p; out2[(size_t)g*32+pos]=(float)p; }
    cnt += (int)__popcll(mask);
    if(cnt>=32) break;
  }
  if(cnt<32){
    for(int j=cnt+lane; j<32; j+=64){ idxw[(size_t)g*32+j]=firstp; out2[(size_t)g*32+j]=(float)firstp; }
  }
}

// ---------------- M = Wq * Wk^T  (3x128) ----------------
__global__ void m_kernel(const float* __restrict__ Wq, const float* __restrict__ Wk, float* __restrict__ M){
  int c = threadIdx.x; // 128
  float m0=0.f,m1=0.f,m2=0.f;
  for(int d=0; d<128; d++){
    float wk = Wk[c*128+d];
    m0 += Wq[d]*wk; m1 += Wq[128+d]*wk; m2 += Wq[256+d]*wk;
  }
  M[c]=m0; M[128+c]=m1; M[256+c]=m2;
}

// ---------------- layer0: gather + (67->64) matmul + bias + partial stats ----------------
__global__ __launch_bounds__(256) void l0_kernel(const float* __restrict__ xyz, const float* __restrict__ pts,
    const float* __restrict__ out0, const int* __restrict__ idxw,
    const float* __restrict__ W0, const float* __restrict__ b0,
    __hip_bfloat16* __restrict__ y0, float* __restrict__ P){
  __shared__ float xl[64*69];
  int tid=threadIdx.x; int base=blockIdx.x*64;
  int w=tid>>6, lane=tid&63;
  for(int i=0;i<16;i++){
    int r=w*16+i; int R=base+r;
    int g=R>>5; int b=g>>10; int p=idxw[R];
    const float* prow = pts + ((size_t)b*4096 + (size_t)p)*64;
    xl[r*69+3+lane] = prow[lane];
    if(lane<3){
      xl[r*69+lane] = fsubr(xyz[((size_t)b*4096+(size_t)p)*3+lane], out0[(size_t)g*3+lane]);
    }
  }
  __syncthreads();
  int r=tid&63;
  int cgu=__builtin_amdgcn_readfirstlane(tid>>6);
  float acc[16];
  #pragma unroll
  for(int j=0;j<16;j++) acc[j]=b0[cgu*16+j];
  for(int c=0;c<67;c++){
    float xv=xl[r*69+c];
    #pragma unroll
    for(int j=0;j<16;j++) acc[j] += xv*W0[c*64+cgu*16+j];
  }
  size_t R=(size_t)base+r;
  unsigned short tb[16];
  #pragma unroll
  for(int j=0;j<16;j++) tb[j]=f2bf(acc[j]);
  uint4* ov=(uint4*)(y0 + R*64 + cgu*16);
  ov[0]=make_uint4(tb[0]|(tb[1]<<16), tb[2]|(tb[3]<<16), tb[4]|(tb[5]<<16), tb[6]|(tb[7]<<16));
  ov[1]=make_uint4(tb[8]|(tb[9]<<16), tb[10]|(tb[11]<<16), tb[12]|(tb[13]<<16), tb[14]|(tb[15]<<16));
  #pragma unroll
  for(int j=0;j<16;j++){
    float s=acc[j], q=acc[j]*acc[j];
    #pragma unroll
    for(int m=32;m>=1;m>>=1){ s+=__shfl_xor(s,m); q+=__shfl_xor(q,m); }
    if(r==0){ P[(size_t)(cgu*16+j)*4096 + blockIdx.x]=s; P[(size_t)(128+cgu*16+j)*4096 + blockIdx.x]=q; }
  }
}

// ---------------- mid layers: bn(prev)+relu on load, matmul, bias, partial stats ----------------
template<int CIN,int COUT>
__global__ __launch_bounds__(256) void lmid_kernel(const __hip_bfloat16* __restrict__ xin,
    const float* __restrict__ ssIn, const float* __restrict__ W, const float* __restrict__ bias,
    __hip_bfloat16* __restrict__ yout, float* __restrict__ P){
  constexpr int STR=CIN+1;
  constexpr int PER=COUT/4;
  __shared__ float xl[64*STR];
  int tid=threadIdx.x; size_t base=(size_t)blockIdx.x*64;
  constexpr int CHUNKS = 64*CIN/8;
  #pragma unroll
  for(int i=0;i<CHUNKS/256;i++){
    int e=i*256+tid;
    int r=e/(CIN/8), c0=(e%(CIN/8))*8;
    uint4 raw = *reinterpret_cast<const uint4*>(xin + (base+(size_t)r)*CIN + c0);
    unsigned u[4]={raw.x,raw.y,raw.z,raw.w};
    #pragma unroll
    for(int k=0;k<4;k++){
      int c=c0+2*k;
      float lo=__uint_as_float(u[k]<<16);
      float hi=__uint_as_float(u[k]&0xFFFF0000u);
      float a=lo*ssIn[c]+ssIn[128+c];
      float bq=hi*ssIn[c+1]+ssIn[128+c+1];
      xl[r*STR+c]  = a>0.f?a:0.f;
      xl[r*STR+c+1]= bq>0.f?bq:0.f;
    }
  }
  __syncthreads();
  int r=tid&63;
  int cgu=__builtin_amdgcn_readfirstlane(tid>>6);
  float acc[PER];
  #pragma unroll
  for(int j=0;j<PER;j++) acc[j]=bias[cgu*PER+j];
  for(int c=0;c<CIN;c++){
    float xv=xl[r*STR+c];
    #pragma unroll
    for(int j=0;j<PER;j++) acc[j] += xv*W[c*COUT+cgu*PER+j];
  }
  size_t R=base+r;
  unsigned short tb[PER];
  #pragma unroll
  for(int j=0;j<PER;j++) tb[j]=f2bf(acc[j]);
  uint4* ov=(uint4*)(yout + R*COUT + cgu*PER);
  #pragma unroll
  for(int v=0;v<PER/8;v++)
    ov[v]=make_uint4(tb[v*8]|(tb[v*8+1]<<16), tb[v*8+2]|(tb[v*8+3]<<16), tb[v*8+4]|(tb[v*8+5]<<16), tb[v*8+6]|(tb[v*8+7]<<16));
  #pragma unroll
  for(int j=0;j<PER;j++){
    float s=acc[j],q=acc[j]*acc[j];
    #pragma unroll
    for(int m=32;m>=1;m>>=1){s+=__shfl_xor(s,m);q+=__shfl_xor(q,m);}
    if(r==0){ P[(size_t)(cgu*PER+j)*4096 + blockIdx.x]=s; P[(size_t)(128+cgu*PER+j)*4096 + blockIdx.x]=q; }
  }
}

// ---------------- finalize stats: scale/shift per channel ----------------
__global__ void fin_kernel(const float* __restrict__ P, const float* __restrict__ gg, const float* __restrict__ be,
                           float* __restrict__ ss){
  int ch=blockIdx.x; int lane=threadIdx.x;
  float s=0.f,q=0.f;
  for(int blk=lane; blk<4096; blk+=64){ s+=P[(size_t)ch*4096+blk]; q+=P[(size_t)(128+ch)*4096+blk]; }
  #pragma unroll
  for(int m=32;m>=1;m>>=1){ s+=__shfl_xor(s,m); q+=__shfl_xor(q,m); }
  if(lane==0){
    const float invNT = 1.0f/262144.0f;
    float mean=s*invNT; float var=q*invNT - mean*mean;
    float scale=gg[ch]/sqrtf(var+1e-3f);
    ss[ch]=scale; ss[128+ch]=be[ch]-mean*scale;
  }
}

// ---------------- per-group: bn2+relu, u=center@M, scores, softmax, hbar ----------------
__global__ __launch_bounds__(256) void sh_kernel(const __hip_bfloat16* __restrict__ y2,
    const float* __restrict__ ss2, const float* __restrict__ M, const float* __restrict__ out0,
    float* __restrict__ hbar){
  __shared__ float h[2][32*130];
  __shared__ float uLds[2][128];
  __shared__ float sLds[2][32];
  int tid=threadIdx.x; int grp=tid>>7, t=tid&127;
  size_t g=(size_t)blockIdx.x*2+grp;
  #pragma unroll
  for(int i=0;i<4;i++){
    int e=i*128+t;
    int row=e>>4, c0=(e&15)*8;
    uint4 raw=*reinterpret_cast<const uint4*>(y2+(g*32+(size_t)row)*128+c0);
    unsigned u[4]={raw.x,raw.y,raw.z,raw.w};
    #pragma unroll
    for(int k=0;k<4;k++){
      int c=c0+2*k;
      float lo=__uint_as_float(u[k]<<16), hi=__uint_as_float(u[k]&0xFFFF0000u);
      float a=lo*ss2[c]+ss2[128+c]; float bq=hi*ss2[c+1]+ss2[128+c+1];
      h[grp][row*130+c]  = a>0.f?a:0.f;
      h[grp][row*130+c+1]= bq>0.f?bq:0.f;
    }
  }
  float cx=out0[g*3], cy=out0[g*3+1], cz=out0[g*3+2];
  uLds[grp][t]=cx*M[t]+cy*M[128+t]+cz*M[256+t];
  __syncthreads();
  if(t<32){
    float sc=0.f;
    for(int c=0;c<128;c++) sc+=h[grp][t*130+c]*uLds[grp][c];
    sc*=0.08838834764831845f; // 1/sqrt(128)
    float mx=sc;
    #pragma unroll
    for(int m=16;m>=1;m>>=1) mx=fmaxf(mx,__shfl_xor(mx,m));
    float p=expf(sc-mx);
    float sum=p;
    #pragma unroll
    for(int m=16;m>=1;m>>=1) sum+=__shfl_xor(sum,m);
    sLds[grp][t]=p/sum;
  }
  __syncthreads();
  float hb=0.f;
  for(int k=0;k<32;k++) hb+=sLds[grp][k]*h[grp][k*130+t];
  hbar[g*128+t]=hb;
}

// ---------------- pooled = hbar @ Wv ----------------
__global__ __launch_bounds__(256) void pool_kernel(const float* __restrict__ hbar, const float* __restrict__ Wv,
    float* __restrict__ out1){
  __shared__ float xl[32*129];
  int tid=threadIdx.x; size_t g0=(size_t)blockIdx.x*32;
  for(int e=tid;e<32*128;e+=256){ int r=e>>7,ch=e&127; xl[r*129+ch]=hbar[(g0+(size_t)r)*128+ch]; }
  __syncthreads();
  int r=tid&31;
  int cgu=__builtin_amdgcn_readfirstlane(tid>>5);
  float acc[16];
  #pragma unroll
  for(int j=0;j<16;j++) acc[j]=0.f;
  for(int c=0;c<128;c++){
    float xv=xl[r*129+c];
    #pragma unroll
    for(int j=0;j<16;j++) acc[j]+=xv*Wv[c*128+cgu*16+j];
  }
  #pragma unroll
  for(int j=0;j<16;j++) out1[(g0+(size_t)r)*128+cgu*16+j]=acc[j];
}

extern "C" void kernel_launch(void* const* d_in, const int* in_sizes, int n_in,
                              void* d_out, int out_size, void* d_ws, size_t ws_size,
                              hipStream_t stream){
  (void)in_sizes; (void)n_in; (void)out_size; (void)ws_size;
  const float* xyz=(const float*)d_in[0];
  const float* pts=(const float*)d_in[1];
  const float* W0=(const float*)d_in[2];  const float* b0=(const float*)d_in[3];
  const float* g0=(const float*)d_in[4];  const float* be0=(const float*)d_in[5];
  const float* W1=(const float*)d_in[6];  const float* b1=(const float*)d_in[7];
  const float* g1=(const float*)d_in[8];  const float* be1=(const float*)d_in[9];
  const float* W2=(const float*)d_in[10]; const float* b2=(const float*)d_in[11];
  const float* g2=(const float*)d_in[12]; const float* be2=(const float*)d_in[13];
  const float* Wq=(const float*)d_in[14]; const float* Wk=(const float*)d_in[15];
  const float* Wv=(const float*)d_in[16];
  float* out0=(float*)d_out;
  float* out1=out0 + (size_t)8*1024*3;
  float* out2=out1 + (size_t)8192*128;

  char* ws=(char*)d_ws; size_t off=0;
  int* idxw=(int*)(ws+off);                    off += (size_t)8192*32*4;
  __hip_bfloat16* fa=(__hip_bfloat16*)(ws+off); off += (size_t)262144*64*2;
  __hip_bfloat16* fb=(__hip_bfloat16*)(ws+off); off += (size_t)262144*64*2;
  __hip_bfloat16* fc=(__hip_bfloat16*)(ws+off); off += (size_t)262144*128*2;
  float* P =(float*)(ws+off);                  off += (size_t)256*4096*4;
  float* ss0=(float*)(ws+off);                 off += 256*4;
  float* ss1=(float*)(ws+off);                 off += 256*4;
  float* ss2=(float*)(ws+off);                 off += 256*4;
  float* M =(float*)(ws+off);                  off += 3*128*4 + 128;
  float* hb=(float*)(ws+off);                  off += (size_t)8192*128*4;

  hipLaunchKernelGGL(fps_kernel,   dim3(8),    dim3(256),  0, stream, xyz, out0);
  hipLaunchKernelGGL(ballq_kernel, dim3(2048), dim3(256),  0, stream, xyz, out0, idxw, out2);
  hipLaunchKernelGGL(m_kernel,     dim3(1),    dim3(128),  0, stream, Wq, Wk, M);
  hipLaunchKernelGGL(l0_kernel,    dim3(4096), dim3(256),  0, stream, xyz, pts, out0, idxw, W0, b0, fa, P);
  hipLaunchKernelGGL(fin_kernel,   dim3(64),   dim3(64),   0, stream, P, g0, be0, ss0);
  hipLaunchKernelGGL((lmid_kernel<64,64>),  dim3(4096), dim3(256), 0, stream, fa, ss0, W1, b1, fb, P);
  hipLaunchKernelGGL(fin_kernel,   dim3(64),   dim3(64),   0, stream, P, g1, be1, ss1);
  hipLaunchKernelGGL((lmid_kernel<64,128>), dim3(4096), dim3(256), 0, stream, fb, ss1, W2, b2, fc, P);
  hipLaunchKernelGGL(fin_kernel,   dim3(128),  dim3(64),   0, stream, P, g2, be2, ss2);
  hipLaunchKernelGGL(sh_kernel,    dim3(4096), dim3(256),  0, stream, fc, ss2, M, out0, hb);
  hipLaunchKernelGGL(pool_kernel,  dim3(256),  dim3(256),  0, stream, hb, Wv, out1);
}